// Round 1
// baseline (2472.240 us; speedup 1.0000x reference)
//
#include <hip/hip_runtime.h>
#include <math.h>

#define NN 8192
// out = elu(0.5*h_s + (sum_j w_ij h_n_j)/Z_i), w_ij = adj_ij * exp(relu(s_i+n_j))

__device__ __forceinline__ float eluf(float x) {
  return x > 0.f ? x : (__expf(x) - 1.f);
}

// ---------------- Kernel 1: h_s = X@W_s -> d_out, h_n = X@W_n -> ws ----------------
// block 256, 32 rows/block, grid 256
__global__ __launch_bounds__(256) void k_proj(const float* __restrict__ X,
                                              const float* __restrict__ Ws,
                                              const float* __restrict__ Wn,
                                              float* __restrict__ Hs,
                                              float* __restrict__ Hn) {
  __shared__ float4 lin4[32 * 64];  // 32 rows x 256 f32 = 32 KB
  const int t = threadIdx.x;
  const int i0 = blockIdx.x * 32;
  const float4* Xg = (const float4*)X + (size_t)i0 * 64;
#pragma unroll
  for (int m = 0; m < 8; ++m) lin4[t + 256 * m] = Xg[t + 256 * m];
  __syncthreads();
  const int c = t & 127;
  const int rh = t >> 7;  // 0..1, 16 rows each
  float accs[16], accn[16];
#pragma unroll
  for (int r = 0; r < 16; ++r) { accs[r] = 0.f; accn[r] = 0.f; }
  for (int k = 0; k < 256; k += 4) {
    float ws0 = Ws[(k + 0) * 128 + c], ws1 = Ws[(k + 1) * 128 + c];
    float ws2 = Ws[(k + 2) * 128 + c], ws3 = Ws[(k + 3) * 128 + c];
    float wn0 = Wn[(k + 0) * 128 + c], wn1 = Wn[(k + 1) * 128 + c];
    float wn2 = Wn[(k + 2) * 128 + c], wn3 = Wn[(k + 3) * 128 + c];
#pragma unroll
    for (int r = 0; r < 16; ++r) {
      float4 iv = lin4[(rh * 16 + r) * 64 + (k >> 2)];  // wave-broadcast
      accs[r] = fmaf(iv.x, ws0, accs[r]); accs[r] = fmaf(iv.y, ws1, accs[r]);
      accs[r] = fmaf(iv.z, ws2, accs[r]); accs[r] = fmaf(iv.w, ws3, accs[r]);
      accn[r] = fmaf(iv.x, wn0, accn[r]); accn[r] = fmaf(iv.y, wn1, accn[r]);
      accn[r] = fmaf(iv.z, wn2, accn[r]); accn[r] = fmaf(iv.w, wn3, accn[r]);
    }
  }
#pragma unroll
  for (int r = 0; r < 16; ++r) {
    size_t row = (size_t)(i0 + rh * 16 + r);
    Hs[row * 128 + c] = accs[r];
    Hn[row * 128 + c] = accn[r];
  }
}

// ---------------- Kernel 2: s = Hs@a_s, n = Hn@a_n ----------------
// block 256 -> 16 rows (16 lanes per row), grid 512
__global__ __launch_bounds__(256) void k_sn(const float* __restrict__ Hs,
                                            const float* __restrict__ Hn,
                                            const float* __restrict__ as_,
                                            const float* __restrict__ an_,
                                            float* __restrict__ s,
                                            float* __restrict__ n) {
  const int t = threadIdx.x;
  const int r = blockIdx.x * 16 + (t >> 4);
  const int l = t & 15;
  float ps = 0.f, pn = 0.f;
#pragma unroll
  for (int m = 0; m < 8; ++m) {
    int c = l + 16 * m;
    ps = fmaf(Hs[(size_t)r * 128 + c], as_[c], ps);
    pn = fmaf(Hn[(size_t)r * 128 + c], an_[c], pn);
  }
#pragma unroll
  for (int off = 8; off >= 1; off >>= 1) {
    ps += __shfl_down(ps, off, 16);
    pn += __shfl_down(pn, off, 16);
  }
  if (l == 0) { s[r] = ps; n[r] = pn; }
}

// ---------------- Kernel 3: fused attention GEMM + softmax-normalize + elu ----------------
__device__ __forceinline__ void load_adj(const int* __restrict__ A, int i0, int bb,
                                         size_t jcol, int* adjv) {
#pragma unroll
  for (int p = 0; p < 4; ++p)
#pragma unroll
    for (int rr = 0; rr < 4; ++rr)
      adjv[p * 4 + rr] = A[(size_t)(i0 + (bb + 2 * p) * 4 + rr) * NN + jcol];
}

__device__ __forceinline__ void compute_w(const int* adjv, const float* sv, float nv,
                                          int jw, int bb, float4* wdst, float* zp) {
#pragma unroll
  for (int p = 0; p < 4; ++p) {
    const int rg = bb + 2 * p;
    float4 wq;
    wq.x = adjv[p * 4 + 0] > 0 ? __expf(fmaxf(sv[p * 4 + 0] + nv, 0.f)) : 0.f;
    wq.y = adjv[p * 4 + 1] > 0 ? __expf(fmaxf(sv[p * 4 + 1] + nv, 0.f)) : 0.f;
    wq.z = adjv[p * 4 + 2] > 0 ? __expf(fmaxf(sv[p * 4 + 2] + nv, 0.f)) : 0.f;
    wq.w = adjv[p * 4 + 3] > 0 ? __expf(fmaxf(sv[p * 4 + 3] + nv, 0.f)) : 0.f;
    zp[p * 4 + 0] += wq.x; zp[p * 4 + 1] += wq.y;
    zp[p * 4 + 2] += wq.z; zp[p * 4 + 3] += wq.w;
    // XOR-swizzled so float4 writes (lanes = consecutive j) tile all 32 banks
    wdst[jw * 8 + (rg ^ (jw & 7))] = wq;
  }
}

// block 256, 32 output rows per block, grid 256; j-tiles of 128 (64 tiles)
__global__ __launch_bounds__(256) void k_main(const int* __restrict__ A,
                                              const float* __restrict__ Hn,
                                              const float* __restrict__ sv_g,
                                              const float* __restrict__ nv_g,
                                              float* __restrict__ HsOut) {
  __shared__ float4 w4[2][128 * 8];  // double-buffered w tile, 2 x 16 KB

  const int t = threadIdx.x;
  const int i0 = blockIdx.x * 32;
  const int tr = t >> 5;   // 0..7  : row-group (4 rows) for FMA/epilogue
  const int tc = t & 31;   // 0..31 : col-group (4 cols)
  const int jw = t & 127;  // j within tile for w-compute
  const int bb = t >> 7;   // 0..1  : row-group base for w-compute

  // s values for this thread's w-compute rows (loop-invariant)
  float sv[16];
#pragma unroll
  for (int p = 0; p < 4; ++p)
#pragma unroll
    for (int rr = 0; rr < 4; ++rr)
      sv[p * 4 + rr] = sv_g[i0 + (bb + 2 * p) * 4 + rr];

  float acc[16], zp[16];
#pragma unroll
  for (int q = 0; q < 16; ++q) { acc[q] = 0.f; zp[q] = 0.f; }

  const float4* Hn4 = (const float4*)Hn;

  // prolog: adj tile 0 -> regs, w tile 0 -> w4[0]
  int adjv[16];
  float nv;
  load_adj(A, i0, bb, (size_t)jw, adjv);
  nv = nv_g[jw];
  compute_w(adjv, sv, nv, jw, bb, &w4[0][0], zp);
  __syncthreads();

  for (int tt = 0; tt < 64; ++tt) {
    const int curb = tt & 1;
    // prefetch next adj tile into registers (overlaps the FMA loop below)
    if (tt < 63) {
      size_t jcol = (size_t)(tt + 1) * 128 + jw;
      load_adj(A, i0, bb, jcol, adjv);
      nv = nv_g[jcol];
    }
    // FMA over this j-tile: w from LDS (broadcast), h_n from global (L2-resident)
    const float4* wsrc = &w4[curb][0];
    const float4* hp = Hn4 + (size_t)tt * 128 * 32 + tc;
#pragma unroll 8
    for (int jj = 0; jj < 128; ++jj) {
      float4 wv = wsrc[jj * 8 + (tr ^ (jj & 7))];
      float4 hv = hp[(size_t)jj * 32];
      acc[0]  = fmaf(wv.x, hv.x, acc[0]);  acc[1]  = fmaf(wv.x, hv.y, acc[1]);
      acc[2]  = fmaf(wv.x, hv.z, acc[2]);  acc[3]  = fmaf(wv.x, hv.w, acc[3]);
      acc[4]  = fmaf(wv.y, hv.x, acc[4]);  acc[5]  = fmaf(wv.y, hv.y, acc[5]);
      acc[6]  = fmaf(wv.y, hv.z, acc[6]);  acc[7]  = fmaf(wv.y, hv.w, acc[7]);
      acc[8]  = fmaf(wv.z, hv.x, acc[8]);  acc[9]  = fmaf(wv.z, hv.y, acc[9]);
      acc[10] = fmaf(wv.z, hv.z, acc[10]); acc[11] = fmaf(wv.z, hv.w, acc[11]);
      acc[12] = fmaf(wv.w, hv.x, acc[12]); acc[13] = fmaf(wv.w, hv.y, acc[13]);
      acc[14] = fmaf(wv.w, hv.z, acc[14]); acc[15] = fmaf(wv.w, hv.w, acc[15]);
    }
    // produce next w tile into the other buffer (adj regs have drained by now)
    if (tt < 63) compute_w(adjv, sv, nv, jw, bb, &w4[curb ^ 1][0], zp);
    __syncthreads();
  }

  // ---- Z reduction: zp (per-thread partials over j) -> per-row Z ----
  float* zs = (float*)&w4[0][0];  // 32 x 128 f32 scratch (16 KB)
  float* zf = (float*)&w4[1][0];  // 32 f32
#pragma unroll
  for (int p = 0; p < 4; ++p)
#pragma unroll
    for (int rr = 0; rr < 4; ++rr)
      zs[((bb + 2 * p) * 4 + rr) * 128 + jw] = zp[p * 4 + rr];
  __syncthreads();
  {
    int row = t >> 3, seg = t & 7;  // 32 rows x 8 threads
    float partial = 0.f;
#pragma unroll
    for (int m = 0; m < 16; ++m) partial += zs[row * 128 + seg * 16 + m];
    partial += __shfl_down(partial, 4, 8);
    partial += __shfl_down(partial, 2, 8);
    partial += __shfl_down(partial, 1, 8);
    if (seg == 0) zf[row] = partial;
  }
  __syncthreads();

  // ---- epilogue: out = elu(0.5*h_s + acc/Z) ----
#pragma unroll
  for (int rr = 0; rr < 4; ++rr) {
    size_t row = (size_t)(i0 + tr * 4 + rr);
    float z = zf[tr * 4 + rr];
    float invz = z > 0.f ? 1.f / z : 0.f;  // z==0 impossible for random adj
    float4 hs = *(const float4*)&HsOut[row * 128 + tc * 4];
    float4 o;
    o.x = eluf(fmaf(acc[rr * 4 + 0], invz, 0.5f * hs.x));
    o.y = eluf(fmaf(acc[rr * 4 + 1], invz, 0.5f * hs.y));
    o.z = eluf(fmaf(acc[rr * 4 + 2], invz, 0.5f * hs.z));
    o.w = eluf(fmaf(acc[rr * 4 + 3], invz, 0.5f * hs.w));
    *(float4*)&HsOut[row * 128 + tc * 4] = o;
  }
}

extern "C" void kernel_launch(void* const* d_in, const int* in_sizes, int n_in,
                              void* d_out, int out_size, void* d_ws, size_t ws_size,
                              hipStream_t stream) {
  const float* X   = (const float*)d_in[0];
  const int*   A   = (const int*)d_in[1];
  const float* Ws  = (const float*)d_in[2];
  const float* as_ = (const float*)d_in[3];
  const float* Wn  = (const float*)d_in[4];
  const float* an_ = (const float*)d_in[5];
  float* out = (float*)d_out;          // holds h_s, then final output (in-place epilogue)
  float* Hn  = (float*)d_ws;           // 8192*128 f32 = 4 MB
  float* s   = Hn + (size_t)NN * 128;  // 8192 f32
  float* n   = s + NN;                 // 8192 f32

  k_proj<<<256, 256, 0, stream>>>(X, Ws, Wn, out, Hn);
  k_sn<<<512, 256, 0, stream>>>(out, Hn, as_, an_, s, n);
  k_main<<<256, 256, 0, stream>>>(A, Hn, s, n, out);
}

// Round 2
// 567.663 us; speedup vs baseline: 4.3551x; 4.3551x over previous
//
#include <hip/hip_runtime.h>
#include <math.h>

#define NN 8192
// out = elu(0.5*h_s + (sum_j w_ij h_n_j)/Z_i), w_ij = adj_ij * exp(relu(s_i+n_j))

typedef short short8 __attribute__((ext_vector_type(8)));   // 8 bf16 (4 VGPRs)
typedef float f32x4 __attribute__((ext_vector_type(4)));

__device__ __forceinline__ float eluf(float x) {
  return x > 0.f ? x : (__expf(x) - 1.f);
}
__device__ __forceinline__ unsigned short f2bf(float f) {
  union { float f; unsigned u; } v; v.f = f;
  unsigned r = v.u + 0x7fffu + ((v.u >> 16) & 1u);  // RNE
  return (unsigned short)(r >> 16);
}

// ---------------- Kernel 1: projections + fused s/n reductions ----------------
// Hs fp32 -> d_out, HnT bf16 [128][8192] -> ws, s=Hs@a_s, n=Hn@a_n -> ws
// block 256, 32 rows/block, grid 256
__global__ __launch_bounds__(256) void k_proj(const float* __restrict__ X,
                                              const float* __restrict__ Ws,
                                              const float* __restrict__ Wn,
                                              const float* __restrict__ as_,
                                              const float* __restrict__ an_,
                                              float* __restrict__ Hs,
                                              unsigned short* __restrict__ HnT,
                                              float* __restrict__ s_out,
                                              float* __restrict__ n_out) {
  __shared__ float4 lin4[32 * 64];  // 32 rows x 256 f32 = 32 KB
  const int t = threadIdx.x;
  const int i0 = blockIdx.x * 32;
  const float4* Xg = (const float4*)X + (size_t)i0 * 64;
#pragma unroll
  for (int m = 0; m < 8; ++m) lin4[t + 256 * m] = Xg[t + 256 * m];
  __syncthreads();
  const int c = t & 127;
  const int rh = t >> 7;  // 0..1, 16 rows each
  float accs[16], accn[16];
#pragma unroll
  for (int r = 0; r < 16; ++r) { accs[r] = 0.f; accn[r] = 0.f; }
  for (int k = 0; k < 256; k += 4) {
    float ws0 = Ws[(k + 0) * 128 + c], ws1 = Ws[(k + 1) * 128 + c];
    float ws2 = Ws[(k + 2) * 128 + c], ws3 = Ws[(k + 3) * 128 + c];
    float wn0 = Wn[(k + 0) * 128 + c], wn1 = Wn[(k + 1) * 128 + c];
    float wn2 = Wn[(k + 2) * 128 + c], wn3 = Wn[(k + 3) * 128 + c];
#pragma unroll
    for (int r = 0; r < 16; ++r) {
      float4 iv = lin4[(rh * 16 + r) * 64 + (k >> 2)];  // wave-broadcast
      accs[r] = fmaf(iv.x, ws0, accs[r]); accs[r] = fmaf(iv.y, ws1, accs[r]);
      accs[r] = fmaf(iv.z, ws2, accs[r]); accs[r] = fmaf(iv.w, ws3, accs[r]);
      accn[r] = fmaf(iv.x, wn0, accn[r]); accn[r] = fmaf(iv.y, wn1, accn[r]);
      accn[r] = fmaf(iv.z, wn2, accn[r]); accn[r] = fmaf(iv.w, wn3, accn[r]);
    }
  }
  // Hs fp32 out
#pragma unroll
  for (int r = 0; r < 16; ++r)
    Hs[(size_t)(i0 + rh * 16 + r) * 128 + c] = accs[r];
  // HnT bf16 out: HnT[f=c][j = i0+rh*16 .. +16]
  {
    unsigned short* hp = HnT + (size_t)c * NN + i0 + rh * 16;
    union { unsigned short us[8]; uint4 u4; } pk;
#pragma unroll
    for (int r = 0; r < 8; ++r) pk.us[r] = f2bf(accn[r]);
    *(uint4*)hp = pk.u4;
#pragma unroll
    for (int r = 0; r < 8; ++r) pk.us[r] = f2bf(accn[8 + r]);
    *(uint4*)(hp + 8) = pk.u4;
  }
  // ---- fused reductions: s[j] = sum_f Hs[j][f]*a_s[f], n likewise ----
  float* red = (float*)lin4;  // 32 x 128 = 16 KB
  __syncthreads();            // lin4 reads done
  {
    float av = as_[c];
#pragma unroll
    for (int r = 0; r < 16; ++r) red[(rh * 16 + r) * 128 + c] = accs[r] * av;
  }
  __syncthreads();
  {
    int row = t >> 3, seg = t & 7;
    float p = 0.f;
#pragma unroll
    for (int m = 0; m < 16; ++m) p += red[row * 128 + seg * 16 + m];
    p += __shfl_down(p, 4, 8); p += __shfl_down(p, 2, 8); p += __shfl_down(p, 1, 8);
    if (seg == 0) s_out[i0 + row] = p;
  }
  __syncthreads();
  {
    float av = an_[c];
#pragma unroll
    for (int r = 0; r < 16; ++r) red[(rh * 16 + r) * 128 + c] = accn[r] * av;
  }
  __syncthreads();
  {
    int row = t >> 3, seg = t & 7;
    float p = 0.f;
#pragma unroll
    for (int m = 0; m < 16; ++m) p += red[row * 128 + seg * 16 + m];
    p += __shfl_down(p, 4, 8); p += __shfl_down(p, 2, 8); p += __shfl_down(p, 1, 8);
    if (seg == 0) n_out[i0 + row] = p;
  }
}

// ---------------- Kernel 2: fused attention GEMM (bf16 MFMA) + softmax + elu --------
// 16 rows/block, block 256 (4 waves), grid 512. j-tiles of 128 (64 tiles).
// Lane (wave=ks, quad=q, m=lane&15) computes A-frag w[m][ks*32+q*8+0..7] directly;
// MFMA phase: every wave reads all 4 ks A-frags from LDS, B-frags from global HnT.
__global__ __launch_bounds__(256) void k_main(const int* __restrict__ A,
                                              const unsigned short* __restrict__ HnT,
                                              const float* __restrict__ sv_g,
                                              const float* __restrict__ nv_g,
                                              float* __restrict__ HsOut) {
  __shared__ short8 fragbuf[2][4][64];  // [buf][ks][lane], 8 KB
  __shared__ float zsh[64];
  __shared__ float zf[16];

  const int t = threadIdx.x;
  const int wv = t >> 6;   // wave 0..3 (= ks for w-compute, f-group for MFMA)
  const int ln = t & 63;
  const int q = ln >> 4;   // quad
  const int m = ln & 15;   // A row / B col / C col
  const int row0 = blockIdx.x * 16;

  const float sm = sv_g[row0 + m];
  const int jlane = wv * 32 + q * 8;
  const int* aptr = A + (size_t)(row0 + m) * NN + jlane;
  const float* nptr = nv_g + jlane;

  // adj prefetch depth 2
  int4 adjv[2][2];
  adjv[0][0] = *(const int4*)(aptr);       adjv[0][1] = *(const int4*)(aptr + 4);
  adjv[1][0] = *(const int4*)(aptr + 128); adjv[1][1] = *(const int4*)(aptr + 132);

  f32x4 acc0 = {0.f, 0.f, 0.f, 0.f}, acc1 = {0.f, 0.f, 0.f, 0.f};
  float zp = 0.f;

  const int f0 = wv * 32 + m;  // B col for this lane (f-tile 0); +16 for tile 1
  const unsigned short* bb0 = HnT + (size_t)f0 * NN + q * 8;
  const unsigned short* bb1 = HnT + (size_t)(f0 + 16) * NN + q * 8;

  for (int tt = 0; tt < 64; ++tt) {
    const int cur = tt & 1;
    // ---- compute w (A-frag) for tile tt ----
    {
      const float4 nA = *(const float4*)(nptr + tt * 128);
      const float4 nB = *(const float4*)(nptr + tt * 128 + 4);
      float nvv[8] = {nA.x, nA.y, nA.z, nA.w, nB.x, nB.y, nB.z, nB.w};
      int av[8] = {adjv[cur][0].x, adjv[cur][0].y, adjv[cur][0].z, adjv[cur][0].w,
                   adjv[cur][1].x, adjv[cur][1].y, adjv[cur][1].z, adjv[cur][1].w};
      short8 fr;
#pragma unroll
      for (int k = 0; k < 8; ++k) {
        float w = av[k] > 0 ? __expf(fmaxf(sm + nvv[k], 0.f)) : 0.f;
        zp += w;
        fr[k] = (short)f2bf(w);
      }
      fragbuf[cur][wv][ln] = fr;
    }
    // ---- prefetch adj for tile tt+2 (stays in flight across the MFMA phase) ----
    if (tt < 62) {
      const int* p = aptr + (tt + 2) * 128;
      adjv[cur][0] = *(const int4*)p;
      adjv[cur][1] = *(const int4*)(p + 4);
    }
    __syncthreads();
    // ---- MFMA phase: 4 K-steps x 2 f-tiles ----
    const int jt = tt * 128;
    short8 a0 = fragbuf[cur][0][ln];
    short8 a1 = fragbuf[cur][1][ln];
    short8 a2 = fragbuf[cur][2][ln];
    short8 a3 = fragbuf[cur][3][ln];
    union { uint4 u; short8 s; } b00, b01, b02, b03, b10, b11, b12, b13;
    b00.u = *(const uint4*)(bb0 + jt);       b10.u = *(const uint4*)(bb1 + jt);
    b01.u = *(const uint4*)(bb0 + jt + 32);  b11.u = *(const uint4*)(bb1 + jt + 32);
    b02.u = *(const uint4*)(bb0 + jt + 64);  b12.u = *(const uint4*)(bb1 + jt + 64);
    b03.u = *(const uint4*)(bb0 + jt + 96);  b13.u = *(const uint4*)(bb1 + jt + 96);
    acc0 = __builtin_amdgcn_mfma_f32_16x16x32_bf16(a0, b00.s, acc0, 0, 0, 0);
    acc1 = __builtin_amdgcn_mfma_f32_16x16x32_bf16(a0, b10.s, acc1, 0, 0, 0);
    acc0 = __builtin_amdgcn_mfma_f32_16x16x32_bf16(a1, b01.s, acc0, 0, 0, 0);
    acc1 = __builtin_amdgcn_mfma_f32_16x16x32_bf16(a1, b11.s, acc1, 0, 0, 0);
    acc0 = __builtin_amdgcn_mfma_f32_16x16x32_bf16(a2, b02.s, acc0, 0, 0, 0);
    acc1 = __builtin_amdgcn_mfma_f32_16x16x32_bf16(a2, b12.s, acc1, 0, 0, 0);
    acc0 = __builtin_amdgcn_mfma_f32_16x16x32_bf16(a3, b03.s, acc0, 0, 0, 0);
    acc1 = __builtin_amdgcn_mfma_f32_16x16x32_bf16(a3, b13.s, acc1, 0, 0, 0);
  }

  // ---- Z reduction: zp is partial for row m over (quad, wave) j-slices ----
  {
    float zz = zp;
    zz += __shfl_down(zz, 32);
    zz += __shfl_down(zz, 16);
    if (ln < 16) zsh[wv * 16 + ln] = zz;
  }
  __syncthreads();
  if (t < 16) zf[t] = 1.f / (zsh[t] + zsh[16 + t] + zsh[32 + t] + zsh[48 + t]);
  __syncthreads();

  // ---- epilogue: out = elu(0.5*h_s + acc/Z); C-layout col=m, row=q*4+reg ----
#pragma unroll
  for (int reg = 0; reg < 4; ++reg) {
    const int row = q * 4 + reg;
    const float invz = zf[row];
    const size_t off = (size_t)(row0 + row) * 128 + f0;
    float h0 = HsOut[off], h1 = HsOut[off + 16];
    HsOut[off]      = eluf(fmaf(acc0[reg], invz, 0.5f * h0));
    HsOut[off + 16] = eluf(fmaf(acc1[reg], invz, 0.5f * h1));
  }
}

extern "C" void kernel_launch(void* const* d_in, const int* in_sizes, int n_in,
                              void* d_out, int out_size, void* d_ws, size_t ws_size,
                              hipStream_t stream) {
  const float* X   = (const float*)d_in[0];
  const int*   A   = (const int*)d_in[1];
  const float* Ws  = (const float*)d_in[2];
  const float* as_ = (const float*)d_in[3];
  const float* Wn  = (const float*)d_in[4];
  const float* an_ = (const float*)d_in[5];
  float* out = (float*)d_out;  // holds h_s, then final output (in-place epilogue)

  unsigned short* HnT = (unsigned short*)d_ws;       // 128*8192 bf16 = 2 MB
  float* s = (float*)(HnT + (size_t)128 * NN);       // 8192 f32
  float* n = s + NN;                                 // 8192 f32

  k_proj<<<256, 256, 0, stream>>>(X, Ws, Wn, as_, an_, out, HnT, s, n);
  k_main<<<512, 256, 0, stream>>>(A, HnT, s, n, out);
}

// Round 3
// 465.997 us; speedup vs baseline: 5.3053x; 1.2182x over previous
//
#include <hip/hip_runtime.h>
#include <math.h>

#define NN 8192
// out = elu(0.5*h_s + (sum_j w_ij h_n_j)/Z_i), w_ij = adj_ij * exp(relu(s_i+n_j))

typedef short short8 __attribute__((ext_vector_type(8)));   // 8 bf16 (4 VGPRs)
typedef float f32x4 __attribute__((ext_vector_type(4)));

__device__ __forceinline__ float eluf(float x) {
  return x > 0.f ? x : (__expf(x) - 1.f);
}
__device__ __forceinline__ unsigned short f2bf(float f) {
  union { float f; unsigned u; } v; v.f = f;
  unsigned r = v.u + 0x7fffu + ((v.u >> 16) & 1u);  // RNE
  return (unsigned short)(r >> 16);
}

// ---------------- Kernel 1: projections + fused s/n reductions ----------------
// 8 rows/block, block 256, grid 1024 (4 blocks/CU -> 16 waves/CU for latency hiding)
__global__ __launch_bounds__(256) void k_proj(const float* __restrict__ X,
                                              const float* __restrict__ Ws,
                                              const float* __restrict__ Wn,
                                              const float* __restrict__ as_,
                                              const float* __restrict__ an_,
                                              float* __restrict__ Hs,
                                              unsigned short* __restrict__ HnT,
                                              float* __restrict__ s_out,
                                              float* __restrict__ n_out) {
  __shared__ float4 lin4[8 * 64];  // 8 rows x 256 f32 = 8 KB
  const int t = threadIdx.x;
  const int i0 = blockIdx.x * 8;
  const float4* Xg = (const float4*)X + (size_t)i0 * 64;
  lin4[t] = Xg[t];
  if (t < 256) lin4[t + 256] = Xg[t + 256];
  __syncthreads();
  const int c = t & 127;
  const int rh = t >> 7;  // 0..1, 4 rows each
  float accs[4], accn[4];
#pragma unroll
  for (int r = 0; r < 4; ++r) { accs[r] = 0.f; accn[r] = 0.f; }
  for (int k = 0; k < 256; k += 4) {
    float ws0 = Ws[(k + 0) * 128 + c], ws1 = Ws[(k + 1) * 128 + c];
    float ws2 = Ws[(k + 2) * 128 + c], ws3 = Ws[(k + 3) * 128 + c];
    float wn0 = Wn[(k + 0) * 128 + c], wn1 = Wn[(k + 1) * 128 + c];
    float wn2 = Wn[(k + 2) * 128 + c], wn3 = Wn[(k + 3) * 128 + c];
#pragma unroll
    for (int r = 0; r < 4; ++r) {
      float4 iv = lin4[(rh * 4 + r) * 64 + (k >> 2)];  // wave-uniform broadcast
      accs[r] = fmaf(iv.x, ws0, accs[r]); accs[r] = fmaf(iv.y, ws1, accs[r]);
      accs[r] = fmaf(iv.z, ws2, accs[r]); accs[r] = fmaf(iv.w, ws3, accs[r]);
      accn[r] = fmaf(iv.x, wn0, accn[r]); accn[r] = fmaf(iv.y, wn1, accn[r]);
      accn[r] = fmaf(iv.z, wn2, accn[r]); accn[r] = fmaf(iv.w, wn3, accn[r]);
    }
  }
  // Hs fp32 out
#pragma unroll
  for (int r = 0; r < 4; ++r)
    Hs[(size_t)(i0 + rh * 4 + r) * 128 + c] = accs[r];
  // HnT bf16 out: HnT[f=c][j = i0+rh*4 .. +4]
  {
    union { unsigned short us[4]; ushort4 u4; } pk;
#pragma unroll
    for (int r = 0; r < 4; ++r) pk.us[r] = f2bf(accn[r]);
    *(ushort4*)(HnT + (size_t)c * NN + i0 + rh * 4) = pk.u4;
  }
  // ---- fused reductions: s[j] = sum_f Hs[j][f]*a_s[f], n likewise ----
  float* red = (float*)lin4;  // 8 x 128 f32 = 4 KB
  const int wv = t >> 6, ln = t & 63;
  __syncthreads();
  {
    float av = as_[c];
#pragma unroll
    for (int r = 0; r < 4; ++r) red[(rh * 4 + r) * 128 + c] = accs[r] * av;
  }
  __syncthreads();
#pragma unroll
  for (int h = 0; h < 2; ++h) {
    int row = wv * 2 + h;
    float p = red[row * 128 + ln] + red[row * 128 + 64 + ln];
#pragma unroll
    for (int off = 32; off >= 1; off >>= 1) p += __shfl_down(p, off);
    if (ln == 0) s_out[i0 + row] = p;
  }
  __syncthreads();
  {
    float av = an_[c];
#pragma unroll
    for (int r = 0; r < 4; ++r) red[(rh * 4 + r) * 128 + c] = accn[r] * av;
  }
  __syncthreads();
#pragma unroll
  for (int h = 0; h < 2; ++h) {
    int row = wv * 2 + h;
    float p = red[row * 128 + ln] + red[row * 128 + 64 + ln];
#pragma unroll
    for (int off = 32; off >= 1; off >>= 1) p += __shfl_down(p, off);
    if (ln == 0) n_out[i0 + row] = p;
  }
}

// ---------------- Kernel 2: fused attention GEMM (bf16 MFMA) + softmax + elu --------
// 16 rows/block, block 256 (4 waves), grid 512. j-tiles of 128 (64 tiles).
// FIFO-friendly VMEM: issue order adj(tt+2), nv(tt+1), B(tt+1); waits are
// vmcnt(8) for nv (B stays in flight) and vmcnt(4) for B (adj stays in flight).
__global__ __launch_bounds__(256) void k_main(const int* __restrict__ A,
                                              const unsigned short* __restrict__ HnT,
                                              const float* __restrict__ sv_g,
                                              const float* __restrict__ nv_g,
                                              float* __restrict__ HsOut) {
  __shared__ short8 fragbuf[2][4][64];  // [buf][ks][lane], 8 KB
  __shared__ float zsh[64];
  __shared__ float zf[16];

  const int t = threadIdx.x;
  const int wv = t >> 6;   // wave 0..3 (= ks for w-compute, f-group for MFMA)
  const int ln = t & 63;
  const int q = ln >> 4;   // quad
  const int m = ln & 15;   // A row / B col / C col
  const int row0 = blockIdx.x * 16;

  const float sm = sv_g[row0 + m];
  const int jlane = wv * 32 + q * 8;
  const int* aptr = A + (size_t)(row0 + m) * NN + jlane;
  const float* nptr = nv_g + jlane;

  const int f0 = wv * 32 + m;  // B col for this lane (f-tile 0); +16 for tile 1
  const unsigned short* bb0 = HnT + (size_t)f0 * NN + q * 8;
  const unsigned short* bb1 = HnT + (size_t)(f0 + 16) * NN + q * 8;

  f32x4 acc0 = {0.f, 0.f, 0.f, 0.f}, acc1 = {0.f, 0.f, 0.f, 0.f};
  float zp = 0.f;

  // prolog issue order: adj(0), adj(1), nv(0), B(0)
  int4 adjv[2][2];
  float4 nvv[2][2];
  union { uint4 u; short8 s; } breg[8];
  adjv[0][0] = *(const int4*)(aptr);       adjv[0][1] = *(const int4*)(aptr + 4);
  adjv[1][0] = *(const int4*)(aptr + 128); adjv[1][1] = *(const int4*)(aptr + 132);
  nvv[0][0] = *(const float4*)(nptr);      nvv[0][1] = *(const float4*)(nptr + 4);
  breg[0].u = *(const uint4*)(bb0);        breg[1].u = *(const uint4*)(bb0 + 32);
  breg[2].u = *(const uint4*)(bb0 + 64);   breg[3].u = *(const uint4*)(bb0 + 96);
  breg[4].u = *(const uint4*)(bb1);        breg[5].u = *(const uint4*)(bb1 + 32);
  breg[6].u = *(const uint4*)(bb1 + 64);   breg[7].u = *(const uint4*)(bb1 + 96);

#pragma unroll 2
  for (int tt = 0; tt < 64; ++tt) {
    const int cur = tt & 1;
    // ---- compute w (A-frag) for tile tt: waits nv(tt)/adj(tt), vmcnt leaves B(tt) in flight
    {
      float nvl[8] = {nvv[cur][0].x, nvv[cur][0].y, nvv[cur][0].z, nvv[cur][0].w,
                      nvv[cur][1].x, nvv[cur][1].y, nvv[cur][1].z, nvv[cur][1].w};
      int av[8] = {adjv[cur][0].x, adjv[cur][0].y, adjv[cur][0].z, adjv[cur][0].w,
                   adjv[cur][1].x, adjv[cur][1].y, adjv[cur][1].z, adjv[cur][1].w};
      short8 fr;
#pragma unroll
      for (int k = 0; k < 8; ++k) {
        float w = av[k] > 0 ? __expf(fmaxf(sm + nvl[k], 0.f)) : 0.f;
        zp += w;
        fr[k] = (short)f2bf(w);
      }
      fragbuf[cur][wv][ln] = fr;
    }
    // ---- issue adj(tt+2), then nv(tt+1) ----
    if (tt < 62) {
      const int* p = aptr + (tt + 2) * 128;
      adjv[cur][0] = *(const int4*)p;
      adjv[cur][1] = *(const int4*)(p + 4);
    }
    if (tt < 63) {
      const float* p = nptr + (tt + 1) * 128;
      nvv[cur ^ 1][0] = *(const float4*)p;
      nvv[cur ^ 1][1] = *(const float4*)(p + 4);
    }
    __syncthreads();
    // ---- MFMA phase: uses breg = B(tt) (waits vmcnt(4): adj stays in flight) ----
    short8 a0 = fragbuf[cur][0][ln];
    short8 a1 = fragbuf[cur][1][ln];
    short8 a2 = fragbuf[cur][2][ln];
    short8 a3 = fragbuf[cur][3][ln];
    acc0 = __builtin_amdgcn_mfma_f32_16x16x32_bf16(a0, breg[0].s, acc0, 0, 0, 0);
    acc1 = __builtin_amdgcn_mfma_f32_16x16x32_bf16(a0, breg[4].s, acc1, 0, 0, 0);
    acc0 = __builtin_amdgcn_mfma_f32_16x16x32_bf16(a1, breg[1].s, acc0, 0, 0, 0);
    acc1 = __builtin_amdgcn_mfma_f32_16x16x32_bf16(a1, breg[5].s, acc1, 0, 0, 0);
    acc0 = __builtin_amdgcn_mfma_f32_16x16x32_bf16(a2, breg[2].s, acc0, 0, 0, 0);
    acc1 = __builtin_amdgcn_mfma_f32_16x16x32_bf16(a2, breg[6].s, acc1, 0, 0, 0);
    acc0 = __builtin_amdgcn_mfma_f32_16x16x32_bf16(a3, breg[3].s, acc0, 0, 0, 0);
    acc1 = __builtin_amdgcn_mfma_f32_16x16x32_bf16(a3, breg[7].s, acc1, 0, 0, 0);
    // ---- issue B(tt+1) (newest in FIFO; only waited next iteration) ----
    if (tt < 63) {
      const size_t jt = (size_t)(tt + 1) * 128;
      breg[0].u = *(const uint4*)(bb0 + jt);      breg[1].u = *(const uint4*)(bb0 + jt + 32);
      breg[2].u = *(const uint4*)(bb0 + jt + 64); breg[3].u = *(const uint4*)(bb0 + jt + 96);
      breg[4].u = *(const uint4*)(bb1 + jt);      breg[5].u = *(const uint4*)(bb1 + jt + 32);
      breg[6].u = *(const uint4*)(bb1 + jt + 64); breg[7].u = *(const uint4*)(bb1 + jt + 96);
    }
  }

  // ---- Z reduction: zp is partial for row m over (quad, wave) j-slices ----
  {
    float zz = zp;
    zz += __shfl_down(zz, 32);
    zz += __shfl_down(zz, 16);
    if (ln < 16) zsh[wv * 16 + ln] = zz;
  }
  __syncthreads();
  if (t < 16) zf[t] = 1.f / (zsh[t] + zsh[16 + t] + zsh[32 + t] + zsh[48 + t]);
  __syncthreads();

  // ---- epilogue: out = elu(0.5*h_s + acc/Z); C-layout col=m, row=q*4+reg ----
#pragma unroll
  for (int reg = 0; reg < 4; ++reg) {
    const int row = q * 4 + reg;
    const float invz = zf[row];
    const size_t off = (size_t)(row0 + row) * 128 + f0;
    float h0 = HsOut[off], h1 = HsOut[off + 16];
    HsOut[off]      = eluf(fmaf(acc0[reg], invz, 0.5f * h0));
    HsOut[off + 16] = eluf(fmaf(acc1[reg], invz, 0.5f * h1));
  }
}

extern "C" void kernel_launch(void* const* d_in, const int* in_sizes, int n_in,
                              void* d_out, int out_size, void* d_ws, size_t ws_size,
                              hipStream_t stream) {
  const float* X   = (const float*)d_in[0];
  const int*   A   = (const int*)d_in[1];
  const float* Ws  = (const float*)d_in[2];
  const float* as_ = (const float*)d_in[3];
  const float* Wn  = (const float*)d_in[4];
  const float* an_ = (const float*)d_in[5];
  float* out = (float*)d_out;  // holds h_s, then final output (in-place epilogue)

  unsigned short* HnT = (unsigned short*)d_ws;       // 128*8192 bf16 = 2 MB
  float* s = (float*)(HnT + (size_t)128 * NN);       // 8192 f32
  float* n = s + NN;                                 // 8192 f32

  k_proj<<<1024, 256, 0, stream>>>(X, Ws, Wn, as_, an_, out, HnT, s, n);
  k_main<<<512, 256, 0, stream>>>(A, HnT, s, n, out);
}